// Round 11
// baseline (338.614 us; speedup 1.0000x reference)
//
#include <hip/hip_runtime.h>
#include <hip/hip_bf16.h>

#define HH 1024
#define LL 512
#define NT 16              // 512/32 row-tiles
#define NTRI 136           // NT*(NT+1)/2 triangular tiles

typedef __attribute__((ext_vector_type(8))) short bf16x8;
typedef __attribute__((ext_vector_type(4))) float f32x4;
typedef __attribute__((ext_vector_type(2))) float f32x2;

static constexpr float C_EXP = 2.8853900817779268f; // 2*log2(e)

// pack 8 fp32 -> 8 bf16 (RNE) as uint4
static __device__ __forceinline__ uint4 pack8(float4 a, float4 b) {
    union { uint4 u; __hip_bfloat162 h[4]; } r;
    r.h[0] = __float22bfloat162_rn(make_float2(a.x, a.y));
    r.h[1] = __float22bfloat162_rn(make_float2(a.z, a.w));
    r.h[2] = __float22bfloat162_rn(make_float2(b.x, b.y));
    r.h[3] = __float22bfloat162_rn(make_float2(b.z, b.w));
    return r.u;
}

// ---------------------------------------------------------------------------
// Kernel 0: fp32->bf16 convert (lm 1MB, W1 4MB) + wsum[c] = sum_h W2[c,h]
// + zero the per-tile combine counters (re-zeroed every launch: graph-safe).
// ---------------------------------------------------------------------------
__global__ __launch_bounds__(256) void convert_kernel(
    const float* __restrict__ lm, const float* __restrict__ W1,
    const float* __restrict__ W2,
    ushort* __restrict__ lm16, ushort* __restrict__ B16,
    float* __restrict__ wsum, uint* __restrict__ cnt)
{
    const int b = blockIdx.x;
    if (b == 1280) {
        const int tid = threadIdx.x;
        if (tid < 128) {
            const int c = tid >> 6, l = tid & 63;
            float s = 0.f;
            for (int q = l; q < 256; q += 64) {
                const float4 v = *(const float4*)&W2[c * HH + q * 4];
                s += v.x + v.y + v.z + v.w;
            }
#pragma unroll
            for (int off = 32; off; off >>= 1) s += __shfl_down(s, off, 64);
            if (l == 0) wsum[c] = s;
        }
        if (tid < NTRI) cnt[tid] = 0;
        return;
    }
    const int q = b * 256 + threadIdx.x;            // 8-elem group
    if (q < 65536) {                                // lm: 512*1024/8
        const float4 a = *(const float4*)&lm[q * 8];
        const float4 c = *(const float4*)&lm[q * 8 + 4];
        ((uint4*)lm16)[q] = pack8(a, c);
    } else {
        const int p = q - 65536;                    // 0..262143
        const int n = p >> 7, k8 = (p & 127) * 8;
        const float* src = &W1[(n & 1023) * 2048 + (n >> 10) * 1024 + k8];
        ((uint4*)B16)[p] = pack8(*(const float4*)src, *(const float4*)(src + 4));
    }
}

// ---------------------------------------------------------------------------
// Kernel 1: bf16 MFMA projection. Tile 64m x 64n, BK=128, grid 256 = 1/CU.
// XCD swizzle for L2 locality.
//   n < 1024:  Ea[m][n] = exp2(C*(acc+b1[n]));  else Eb[m][n-1024] = exp2(C*acc)
// ---------------------------------------------------------------------------
__global__ __launch_bounds__(256, 4) void proj_mfma_kernel(
    const ushort* __restrict__ lm16, const ushort* __restrict__ B16,
    const float* __restrict__ b1, float* __restrict__ Ea, float* __restrict__ Eb)
{
    __shared__ ushort As[64][136];  // 136 us = 68 dw = 4 mod 32 banks: <=2-way, free
    __shared__ ushort Bs[64][136];

    const int tid  = threadIdx.x;
    const int lane = tid & 63;
    const int w    = tid >> 6;
    const int b    = blockIdx.x;          // 0..255
    const int xcd  = b & 7;
    const int idx  = b >> 3;              // 0..31
    const int nbase = (xcd * 4 + (idx & 3)) * 64;   // 0..2047
    const int mbase = (idx >> 2) * 64;              // 0..448
    const int wm   = w * 16;

    const int frow = lane & 15;
    const int q8   = (lane >> 4) * 8;

    f32x4 acc[4] = {};

    for (int kb = 0; kb < HH; kb += 128) {
        __syncthreads();
        {   // As/Bs: 64 rows x 128 bf16 = 1024 uint4 slots each, 4/thread each
            int p = tid;
#pragma unroll
            for (int it = 0; it < 4; ++it, p += 256) {
                const int row = p >> 4, c8 = (p & 15) * 8;
                *(uint4*)&As[row][c8] = *(const uint4*)&lm16[(mbase + row) * HH + kb + c8];
                *(uint4*)&Bs[row][c8] = *(const uint4*)&B16[(nbase + row) * HH + kb + c8];
            }
        }
        __syncthreads();

#pragma unroll
        for (int s = 0; s < 4; ++s) {
            const bf16x8 a = *(const bf16x8*)&As[wm + frow][s * 32 + q8];
#pragma unroll
            for (int nf = 0; nf < 4; ++nf) {
                const bf16x8 bb = *(const bf16x8*)&Bs[nf * 16 + frow][s * 32 + q8];
                acc[nf] = __builtin_amdgcn_mfma_f32_16x16x32_bf16(a, bb, acc[nf], 0, 0, 0);
            }
        }
    }

    // D mapping: col=lane&15 (n), row=(lane>>4)*4+reg (m)
    const int col = lane & 15;
    const int rq  = (lane >> 4) * 4;
    const int m0  = mbase + wm + rq;
    const bool isA = nbase < HH;          // block-uniform
#pragma unroll
    for (int nf = 0; nf < 4; ++nf) {
        const int nn = (nbase + nf * 16 + col) & 1023;
        if (isA) {
            const float bb = b1[nn];
#pragma unroll
            for (int r = 0; r < 4; ++r)
                Ea[(m0 + r) * HH + nn] = __builtin_amdgcn_exp2f(C_EXP * (acc[nf][r] + bb));
        } else {
#pragma unroll
            for (int r = 0; r < 4; ++r)
                Eb[(m0 + r) * HH + nn] = __builtin_amdgcn_exp2f(C_EXP * acc[nf][r]);
        }
    }
}

// ---------------------------------------------------------------------------
// Kernel 2: triangular pairwise contraction (R10 packed inner loop) with the
// combine fused as a split-K last-block reduction: every block stores its
// slice partial, fence+atomic counter; the (nz-1)th arriver for a tile sums
// the nz partials and writes out (i,j) and (j,i).
// ---------------------------------------------------------------------------
__global__ __launch_bounds__(256, 4) void pair_kernel(
    const float* __restrict__ Ea, const float* __restrict__ Eb,
    const float* __restrict__ W2, const float* __restrict__ b2,
    const float* __restrict__ wsum, float* __restrict__ pbuf,
    uint* __restrict__ cnt, float* __restrict__ out, int slice, int nz)
{
    __shared__ float eaj[32][68];   // stride 68 = 4 mod 32 banks: <=2-way, free
    __shared__ float eai[32][68];
    __shared__ float ebi[32][68];
    __shared__ float ebj[32][68];
    __shared__ f32x2 ws2[128];      // interleaved {w0[h], w1[h]}
    __shared__ int  s_last;

    const int tid = threadIdx.x;
    const int tx  = tid & 15;
    const int ty  = tid >> 4;

    int tt = blockIdx.x, bi = 0, rem = NT;          // triangular decode
    while (tt >= rem) { tt -= rem; --rem; ++bi; }
    const int bj    = bi + tt;
    const int ibase = bi * 32;
    const int jbase = bj * 32;
    const int k0    = blockIdx.y * slice;

    if (tid < slice)   // stage W2 interleaved
        ws2[tid] = (f32x2){W2[k0 + tid], W2[HH + k0 + tid]};

    f32x2 acc2[2][2] = {};  // [ii][jj], lanes = c-channels
    const f32x2 one2 = {1.f, 1.f};

    for (int kb = 0; kb < slice; kb += 64) {
        __syncthreads();
        {   // stage 4 tiles x 32 rows x 64 floats = 2048 float4, 8/thread
            int p = tid;
#pragma unroll
            for (int it = 0; it < 8; ++it, p += 256) {
                const int tile = p >> 9;
                const int row  = (p >> 4) & 31;
                const int c4   = p & 15;
                float4 v;
                if      (tile == 0) v = *(const float4*)&Ea[(jbase + row) * HH + k0 + kb + c4 * 4];
                else if (tile == 1) v = *(const float4*)&Ea[(ibase + row) * HH + k0 + kb + c4 * 4];
                else if (tile == 2) v = *(const float4*)&Eb[(ibase + row) * HH + k0 + kb + c4 * 4];
                else                v = *(const float4*)&Eb[(jbase + row) * HH + k0 + kb + c4 * 4];
                if      (tile == 0) *(float4*)&eaj[row][c4 * 4] = v;
                else if (tile == 1) *(float4*)&eai[row][c4 * 4] = v;
                else if (tile == 2) *(float4*)&ebi[row][c4 * 4] = v;
                else                *(float4*)&ebj[row][c4 * 4] = v;
            }
        }
        __syncthreads();

#pragma unroll 4
        for (int h4 = 0; h4 < 16; ++h4) {
            const float4 Aj0 = *(const float4*)&eaj[tx][h4 * 4];
            const float4 Aj1 = *(const float4*)&eaj[tx + 16][h4 * 4];
            const float4 Bi0 = *(const float4*)&ebi[ty][h4 * 4];
            const float4 Bi1 = *(const float4*)&ebi[ty + 16][h4 * 4];
            const float4 Ai0 = *(const float4*)&eai[ty][h4 * 4];
            const float4 Ai1 = *(const float4*)&eai[ty + 16][h4 * 4];
            const float4 Bj0 = *(const float4*)&ebj[tx][h4 * 4];
            const float4 Bj1 = *(const float4*)&ebj[tx + 16][h4 * 4];
            const f32x4 wA = *(const f32x4*)&ws2[kb + h4 * 4];      // {w01[h0], w01[h1]}
            const f32x4 wB = *(const f32x4*)&ws2[kb + h4 * 4 + 2];  // {w01[h2], w01[h3]}

#define DO_H(AJ0v, AJ1v, BI0v, BI1v, AI0v, AI1v, BJ0v, BJ1v, W01)            \
            {                                                                 \
                const f32x2 Aj = {AJ0v, AJ1v};                                \
                const f32x2 Bj = {BJ0v, BJ1v};                                \
                const f32x2 d0 = __builtin_elementwise_fma((f32x2){BI0v, BI0v}, Aj, one2); \
                const f32x2 d1 = __builtin_elementwise_fma((f32x2){BI1v, BI1v}, Aj, one2); \
                const f32x2 e0 = __builtin_elementwise_fma((f32x2){AI0v, AI0v}, Bj, one2); \
                const f32x2 e1 = __builtin_elementwise_fma((f32x2){AI1v, AI1v}, Bj, one2); \
                const float dp0 = d0.x * d0.y, dp1 = d1.x * d1.y;             \
                const float ep0 = e0.x * e0.y, ep1 = e1.x * e1.y;             \
                const float DR = __builtin_amdgcn_rcpf(dp0 * dp1);            \
                const float ER = __builtin_amdgcn_rcpf(ep0 * ep1);            \
                const f32x2 dq = (f32x2){DR, DR} * (f32x2){dp1, dp0};         \
                const f32x2 eq = (f32x2){ER, ER} * (f32x2){ep1, ep0};         \
                const f32x2 u0 = (f32x2){dq.x, dq.x} * d0.yx + (f32x2){eq.x, eq.x} * e0.yx; \
                const f32x2 u1 = (f32x2){dq.y, dq.y} * d1.yx + (f32x2){eq.y, eq.y} * e1.yx; \
                acc2[0][0] = __builtin_elementwise_fma((f32x2){u0.x, u0.x}, (W01), acc2[0][0]); \
                acc2[0][1] = __builtin_elementwise_fma((f32x2){u0.y, u0.y}, (W01), acc2[0][1]); \
                acc2[1][0] = __builtin_elementwise_fma((f32x2){u1.x, u1.x}, (W01), acc2[1][0]); \
                acc2[1][1] = __builtin_elementwise_fma((f32x2){u1.y, u1.y}, (W01), acc2[1][1]); \
            }
            DO_H(Aj0.x, Aj1.x, Bi0.x, Bi1.x, Ai0.x, Ai1.x, Bj0.x, Bj1.x, wA.xy)
            DO_H(Aj0.y, Aj1.y, Bi0.y, Bi1.y, Ai0.y, Ai1.y, Bj0.y, Bj1.y, wA.zw)
            DO_H(Aj0.z, Aj1.z, Bi0.z, Bi1.z, Ai0.z, Ai1.z, Bj0.z, Bj1.z, wB.xy)
            DO_H(Aj0.w, Aj1.w, Bi0.w, Bi1.w, Ai0.w, Ai1.w, Bj0.w, Bj1.w, wB.zw)
#undef DO_H
        }
    }

    // store this block's slice partial
    float* pb = pbuf + ((size_t)blockIdx.y * NTRI + blockIdx.x) * 2048;
#pragma unroll
    for (int ii = 0; ii < 2; ++ii)
#pragma unroll
        for (int jj = 0; jj < 2; ++jj) {
            const int li = ty + ii * 16, lj = tx + jj * 16;
            *(f32x2*)&pb[(li * 32 + lj) * 2] = acc2[ii][jj];
        }

    // last-block-per-tile combine (split-K reduction, device-scope)
    __threadfence();                       // release: drain stores, L2 wb
    if (tid == 0) {
        const uint old = atomicAdd(&cnt[blockIdx.x], 1u);
        s_last = (old == (uint)(nz - 1));
    }
    __syncthreads();
    if (!s_last) return;
    __threadfence();                       // acquire: see other XCDs' partials

    const float base0 = wsum[0] + b2[0];
    const float base1 = wsum[1] + b2[1];
#pragma unroll
    for (int k = 0; k < 8; ++k) {
        const int local = k * 256 + tid;   // li*64 + lj*2 + c
        float s0 = 0.f, s1 = 0.f;
        for (int z = 0; z < nz; z += 2) {  // nz even
            s0 += pbuf[((size_t)z * NTRI + blockIdx.x) * 2048 + local];
            s1 += pbuf[((size_t)(z + 1) * NTRI + blockIdx.x) * 2048 + local];
        }
        const int li = local >> 6;
        const int lj = (local >> 1) & 31;
        const int c  = local & 1;
        const float v = (c ? base1 : base0) - (s0 + s1);
        const int i = ibase + li;
        const int j = jbase + lj;
        out[(i * LL + j) * 2 + c] = v;
        out[(j * LL + i) * 2 + c] = v;     // diagonal tiles: benign rewrite
    }
}

extern "C" void kernel_launch(void* const* d_in, const int* in_sizes, int n_in,
                              void* d_out, int out_size, void* d_ws, size_t ws_size,
                              hipStream_t stream)
{
    const float* lm = (const float*)d_in[0];
    const float* W1 = (const float*)d_in[1];
    const float* b1 = (const float*)d_in[2];
    const float* W2 = (const float*)d_in[3];
    const float* b2 = (const float*)d_in[4];
    float* out = (float*)d_out;

    char* ws = (char*)d_ws;
    float*  Ea   = (float*)ws;                           // 2 MB
    float*  Eb   = (float*)(ws + (2u << 20));            // 2 MB
    float*  wsum = (float*)(ws + (4u << 20));            // 8 B
    uint*   cnt  = (uint*) (ws + (4u << 20) + 64);       // 544 B
    // Union region: {lm16 1MB, B16 4MB} live until proj finishes; pbuf
    // (written by pair, after proj) aliases over them.
    char*   ub   = ws + (4u << 20) + 1024;
    ushort* lm16 = (ushort*)ub;
    ushort* B16  = (ushort*)(ub + (1u << 20));
    float*  pbuf = (float*)ub;

    const size_t ubase  = (4u << 20) + 1024;
    const size_t pb16   = (size_t)16 * NTRI * 2048 * 4;  // 17.8 MB
    const int nz = (ws_size >= ubase + pb16) ? 16 : 8;   // ws_size const/session
    const int slice = HH / nz;

    convert_kernel<<<1281, 256, 0, stream>>>(lm, W1, W2, lm16, B16, wsum, cnt);
    proj_mfma_kernel<<<256, 256, 0, stream>>>(lm16, B16, b1, Ea, Eb);
    pair_kernel<<<dim3(NTRI, nz), 256, 0, stream>>>(Ea, Eb, W2, b2, wsum,
                                                    pbuf, cnt, out, slice, nz);
}

// Round 12
// 129.450 us; speedup vs baseline: 2.6158x; 2.6158x over previous
//
#include <hip/hip_runtime.h>
#include <hip/hip_bf16.h>

#define HH 1024
#define LL 512
#define NT 16              // 512/32 row-tiles
#define NTRI 136           // NT*(NT+1)/2 triangular tiles

typedef __attribute__((ext_vector_type(8))) short bf16x8;
typedef __attribute__((ext_vector_type(4))) float f32x4;
typedef __attribute__((ext_vector_type(2))) float f32x2;

static constexpr float C_EXP = 2.8853900817779268f; // 2*log2(e)

// pack 8 fp32 -> 8 bf16 (RNE) as uint4
static __device__ __forceinline__ uint4 pack8(float4 a, float4 b) {
    union { uint4 u; __hip_bfloat162 h[4]; } r;
    r.h[0] = __float22bfloat162_rn(make_float2(a.x, a.y));
    r.h[1] = __float22bfloat162_rn(make_float2(a.z, a.w));
    r.h[2] = __float22bfloat162_rn(make_float2(b.x, b.y));
    r.h[3] = __float22bfloat162_rn(make_float2(b.z, b.w));
    return r.u;
}

// ---------------------------------------------------------------------------
// Kernel 1: bf16 MFMA projection with fp32->bf16 fused into LDS staging
// (convert kernel deleted). Tile 64m x 64n, BK=128, grid 256 = 1/CU.
// XCD swizzle: per-XCD fp32 working set = 1MB W1-slice + 2MB lm < 4MB L2,
// so re-reads are L2-served despite fp32 width.
//   n < 1024:  Ea[m][n] = exp2(C*(acc+b1[n]));  else Eb[m][n-1024] = exp2(C*acc)
// ---------------------------------------------------------------------------
__global__ __launch_bounds__(256, 4) void proj_mfma_kernel(
    const float* __restrict__ lm, const float* __restrict__ W1,
    const float* __restrict__ b1, float* __restrict__ Ea, float* __restrict__ Eb)
{
    __shared__ ushort As[64][136];  // 136 us = 68 dw = 4 mod 32 banks: <=2-way, free
    __shared__ ushort Bs[64][136];

    const int tid  = threadIdx.x;
    const int lane = tid & 63;
    const int w    = tid >> 6;
    const int b    = blockIdx.x;          // 0..255
    const int xcd  = b & 7;
    const int idx  = b >> 3;              // 0..31
    const int nbase = (xcd * 4 + (idx & 3)) * 64;   // 0..2047
    const int mbase = (idx >> 2) * 64;              // 0..448
    const int wm   = w * 16;
    const int sel  = nbase >> 10;         // block-uniform: Wa(0)/Wb(1)
    const int nrow = nbase & 1023;

    const int frow = lane & 15;
    const int q8   = (lane >> 4) * 8;

    f32x4 acc[4] = {};

    for (int kb = 0; kb < HH; kb += 128) {
        __syncthreads();
        {   // As/Bs: 64 rows x 128 bf16 = 1024 uint4 slots each, 4/thread each
            int p = tid;
#pragma unroll
            for (int it = 0; it < 4; ++it, p += 256) {
                const int row = p >> 4, c8 = (p & 15) * 8;
                const float* pa = &lm[(mbase + row) * HH + kb + c8];
                *(uint4*)&As[row][c8] = pack8(*(const float4*)pa, *(const float4*)(pa + 4));
                const float* pw = &W1[(nrow + row) * 2048 + sel * 1024 + kb + c8];
                *(uint4*)&Bs[row][c8] = pack8(*(const float4*)pw, *(const float4*)(pw + 4));
            }
        }
        __syncthreads();

#pragma unroll
        for (int s = 0; s < 4; ++s) {
            const bf16x8 a = *(const bf16x8*)&As[wm + frow][s * 32 + q8];
#pragma unroll
            for (int nf = 0; nf < 4; ++nf) {
                const bf16x8 bb = *(const bf16x8*)&Bs[nf * 16 + frow][s * 32 + q8];
                acc[nf] = __builtin_amdgcn_mfma_f32_16x16x32_bf16(a, bb, acc[nf], 0, 0, 0);
            }
        }
    }

    // D mapping: col=lane&15 (n), row=(lane>>4)*4+reg (m)
    const int col = lane & 15;
    const int rq  = (lane >> 4) * 4;
    const int m0  = mbase + wm + rq;
    const bool isA = sel == 0;            // block-uniform
#pragma unroll
    for (int nf = 0; nf < 4; ++nf) {
        const int nn = (nrow + nf * 16 + col);
        if (isA) {
            const float bb = b1[nn];
#pragma unroll
            for (int r = 0; r < 4; ++r)
                Ea[(m0 + r) * HH + nn] = __builtin_amdgcn_exp2f(C_EXP * (acc[nf][r] + bb));
        } else {
#pragma unroll
            for (int r = 0; r < 4; ++r)
                Eb[(m0 + r) * HH + nn] = __builtin_amdgcn_exp2f(C_EXP * acc[nf][r]);
        }
    }
}

// ---------------------------------------------------------------------------
// Kernel 2: triangular pairwise contraction (exact R10 form — measured 48us).
// Inner math on float2 ext-vectors (v_pk_*_f32); W2 staged interleaved;
// batched rcp (1 per 4 denominators per direction). Plain stores, no atomics.
// ---------------------------------------------------------------------------
__global__ __launch_bounds__(256, 4) void pair_kernel(
    const float* __restrict__ Ea, const float* __restrict__ Eb,
    const float* __restrict__ W2, float* __restrict__ pbuf, int slice)
{
    __shared__ float eaj[32][68];   // stride 68 = 4 mod 32 banks: <=2-way, free
    __shared__ float eai[32][68];
    __shared__ float ebi[32][68];
    __shared__ float ebj[32][68];
    __shared__ f32x2 ws2[128];      // interleaved {w0[h], w1[h]}

    const int tid = threadIdx.x;
    const int tx  = tid & 15;
    const int ty  = tid >> 4;

    int tt = blockIdx.x, bi = 0, rem = NT;          // triangular decode
    while (tt >= rem) { tt -= rem; --rem; ++bi; }
    const int bj    = bi + tt;
    const int ibase = bi * 32;
    const int jbase = bj * 32;
    const int k0    = blockIdx.y * slice;

    if (tid < slice)   // stage W2 interleaved
        ws2[tid] = (f32x2){W2[k0 + tid], W2[HH + k0 + tid]};

    f32x2 acc2[2][2] = {};  // [ii][jj], lanes = c-channels
    const f32x2 one2 = {1.f, 1.f};

    for (int kb = 0; kb < slice; kb += 64) {
        __syncthreads();
        {   // stage 4 tiles x 32 rows x 64 floats = 2048 float4, 8/thread
            int p = tid;
#pragma unroll
            for (int it = 0; it < 8; ++it, p += 256) {
                const int tile = p >> 9;
                const int row  = (p >> 4) & 31;
                const int c4   = p & 15;
                float4 v;
                if      (tile == 0) v = *(const float4*)&Ea[(jbase + row) * HH + k0 + kb + c4 * 4];
                else if (tile == 1) v = *(const float4*)&Ea[(ibase + row) * HH + k0 + kb + c4 * 4];
                else if (tile == 2) v = *(const float4*)&Eb[(ibase + row) * HH + k0 + kb + c4 * 4];
                else                v = *(const float4*)&Eb[(jbase + row) * HH + k0 + kb + c4 * 4];
                if      (tile == 0) *(float4*)&eaj[row][c4 * 4] = v;
                else if (tile == 1) *(float4*)&eai[row][c4 * 4] = v;
                else if (tile == 2) *(float4*)&ebi[row][c4 * 4] = v;
                else                *(float4*)&ebj[row][c4 * 4] = v;
            }
        }
        __syncthreads();

#pragma unroll 4
        for (int h4 = 0; h4 < 16; ++h4) {
            const float4 Aj0 = *(const float4*)&eaj[tx][h4 * 4];
            const float4 Aj1 = *(const float4*)&eaj[tx + 16][h4 * 4];
            const float4 Bi0 = *(const float4*)&ebi[ty][h4 * 4];
            const float4 Bi1 = *(const float4*)&ebi[ty + 16][h4 * 4];
            const float4 Ai0 = *(const float4*)&eai[ty][h4 * 4];
            const float4 Ai1 = *(const float4*)&eai[ty + 16][h4 * 4];
            const float4 Bj0 = *(const float4*)&ebj[tx][h4 * 4];
            const float4 Bj1 = *(const float4*)&ebj[tx + 16][h4 * 4];
            const f32x4 wA = *(const f32x4*)&ws2[kb + h4 * 4];      // {w01[h0], w01[h1]}
            const f32x4 wB = *(const f32x4*)&ws2[kb + h4 * 4 + 2];  // {w01[h2], w01[h3]}

#define DO_H(AJ0v, AJ1v, BI0v, BI1v, AI0v, AI1v, BJ0v, BJ1v, W01)            \
            {                                                                 \
                const f32x2 Aj = {AJ0v, AJ1v};                                \
                const f32x2 Bj = {BJ0v, BJ1v};                                \
                const f32x2 d0 = __builtin_elementwise_fma((f32x2){BI0v, BI0v}, Aj, one2); \
                const f32x2 d1 = __builtin_elementwise_fma((f32x2){BI1v, BI1v}, Aj, one2); \
                const f32x2 e0 = __builtin_elementwise_fma((f32x2){AI0v, AI0v}, Bj, one2); \
                const f32x2 e1 = __builtin_elementwise_fma((f32x2){AI1v, AI1v}, Bj, one2); \
                const float dp0 = d0.x * d0.y, dp1 = d1.x * d1.y;             \
                const float ep0 = e0.x * e0.y, ep1 = e1.x * e1.y;             \
                const float DR = __builtin_amdgcn_rcpf(dp0 * dp1);            \
                const float ER = __builtin_amdgcn_rcpf(ep0 * ep1);            \
                const f32x2 dq = (f32x2){DR, DR} * (f32x2){dp1, dp0};         \
                const f32x2 eq = (f32x2){ER, ER} * (f32x2){ep1, ep0};         \
                const f32x2 u0 = (f32x2){dq.x, dq.x} * d0.yx + (f32x2){eq.x, eq.x} * e0.yx; \
                const f32x2 u1 = (f32x2){dq.y, dq.y} * d1.yx + (f32x2){eq.y, eq.y} * e1.yx; \
                acc2[0][0] = __builtin_elementwise_fma((f32x2){u0.x, u0.x}, (W01), acc2[0][0]); \
                acc2[0][1] = __builtin_elementwise_fma((f32x2){u0.y, u0.y}, (W01), acc2[0][1]); \
                acc2[1][0] = __builtin_elementwise_fma((f32x2){u1.x, u1.x}, (W01), acc2[1][0]); \
                acc2[1][1] = __builtin_elementwise_fma((f32x2){u1.y, u1.y}, (W01), acc2[1][1]); \
            }
            DO_H(Aj0.x, Aj1.x, Bi0.x, Bi1.x, Ai0.x, Ai1.x, Bj0.x, Bj1.x, wA.xy)
            DO_H(Aj0.y, Aj1.y, Bi0.y, Bi1.y, Ai0.y, Ai1.y, Bj0.y, Bj1.y, wA.zw)
            DO_H(Aj0.z, Aj1.z, Bi0.z, Bi1.z, Ai0.z, Ai1.z, Bj0.z, Bj1.z, wB.xy)
            DO_H(Aj0.w, Aj1.w, Bi0.w, Bi1.w, Ai0.w, Ai1.w, Bj0.w, Bj1.w, wB.zw)
#undef DO_H
        }
    }

    float* pb = pbuf + ((size_t)blockIdx.y * NTRI + blockIdx.x) * 2048;
#pragma unroll
    for (int ii = 0; ii < 2; ++ii)
#pragma unroll
        for (int jj = 0; jj < 2; ++jj) {
            const int li = ty + ii * 16, lj = tx + jj * 16;
            *(f32x2*)&pb[(li * 32 + lj) * 2] = acc2[ii][jj];
        }
}

// ---------------------------------------------------------------------------
// Kernel 3: combine (R10 structure, wsum computed in-block from W2):
//   out = wsum[c] + b2[c] - sum_z pbuf; scatter to (i,j) and (j,i).
// 1088 blocks, 1 thread/elem, 2-way ILP on z-accumulation.
// ---------------------------------------------------------------------------
__global__ __launch_bounds__(256) void combine_kernel(
    const float* __restrict__ pbuf, const float* __restrict__ W2,
    const float* __restrict__ b2, float* __restrict__ out, int nz)
{
    __shared__ float s_ws[2];

    const int tid = threadIdx.x;
    // in-block wsum: 128 threads, c = tid>>6, 4 float4 each over W2[c]
    if (tid < 128) {
        const int c = tid >> 6, l = tid & 63;
        float s = 0.f;
#pragma unroll
        for (int q = 0; q < 4; ++q) {
            const float4 v = *(const float4*)&W2[c * HH + (l + q * 64) * 4];
            s += v.x + v.y + v.z + v.w;
        }
#pragma unroll
        for (int off = 32; off; off >>= 1) s += __shfl_down(s, off, 64);
        if (l == 0) s_ws[c] = s + b2[c];
    }
    __syncthreads();

    const int idx   = blockIdx.x * 256 + tid;   // 0 .. 136*2048-1
    const int t     = idx >> 11;                // block-uniform (2048 = 8 blocks)
    const int local = idx & 2047;
    int tt = t, bi = 0, rem = NT;
    while (tt >= rem) { tt -= rem; --rem; ++bi; }
    const int bj = bi + tt;

    float s0 = 0.f, s1 = 0.f;
    for (int z = 0; z < nz; z += 2) {   // nz is even
        s0 += pbuf[((size_t)z * NTRI + t) * 2048 + local];
        s1 += pbuf[((size_t)(z + 1) * NTRI + t) * 2048 + local];
    }
    const float s = s0 + s1;

    const int li = local >> 6;
    const int lj = (local >> 1) & 31;
    const int c  = local & 1;
    const float v = s_ws[c] - s;

    const int i = bi * 32 + li;
    const int j = bj * 32 + lj;
    out[(i * LL + j) * 2 + c] = v;
    out[(j * LL + i) * 2 + c] = v;   // diagonal tiles: same-value rewrite, benign
}

extern "C" void kernel_launch(void* const* d_in, const int* in_sizes, int n_in,
                              void* d_out, int out_size, void* d_ws, size_t ws_size,
                              hipStream_t stream)
{
    const float* lm = (const float*)d_in[0];
    const float* W1 = (const float*)d_in[1];
    const float* b1 = (const float*)d_in[2];
    const float* W2 = (const float*)d_in[3];
    const float* b2 = (const float*)d_in[4];
    float* out = (float*)d_out;

    char* ws = (char*)d_ws;
    float* Ea   = (float*)ws;                            // 2 MB
    float* Eb   = (float*)(ws + (2u << 20));             // 2 MB
    float* pbuf = (float*)(ws + (4u << 20) + 64);        // nz * 1.11 MB

    const size_t ubase = (4u << 20) + 64;
    const size_t pb16  = (size_t)16 * NTRI * 2048 * 4;   // 17.8 MB
    const int nz = (ws_size >= ubase + pb16) ? 16 : 8;   // ws_size const/session
    const int slice = HH / nz;

    proj_mfma_kernel<<<256, 256, 0, stream>>>(lm, W1, b1, Ea, Eb);
    pair_kernel<<<dim3(NTRI, nz), 256, 0, stream>>>(Ea, Eb, W2, pbuf, slice);
    combine_kernel<<<(NTRI * 2048) / 256, 256, 0, stream>>>(pbuf, W2, b2, out, nz);
}

// Round 13
// 129.200 us; speedup vs baseline: 2.6209x; 1.0019x over previous
//
#include <hip/hip_runtime.h>
#include <hip/hip_bf16.h>

#define HH 1024
#define LL 512
#define NT 16              // 512/32 row-tiles
#define NTRI 136           // NT*(NT+1)/2 triangular tiles

typedef __attribute__((ext_vector_type(8))) short bf16x8;
typedef __attribute__((ext_vector_type(4))) float f32x4;
typedef __attribute__((ext_vector_type(2))) float f32x2;

static constexpr float C_EXP = 2.8853900817779268f; // 2*log2(e)

// pack 8 fp32 -> 8 bf16 (RNE) as uint4
static __device__ __forceinline__ uint4 pack8(float4 a, float4 b) {
    union { uint4 u; __hip_bfloat162 h[4]; } r;
    r.h[0] = __float22bfloat162_rn(make_float2(a.x, a.y));
    r.h[1] = __float22bfloat162_rn(make_float2(a.z, a.w));
    r.h[2] = __float22bfloat162_rn(make_float2(b.x, b.y));
    r.h[3] = __float22bfloat162_rn(make_float2(b.z, b.w));
    return r.u;
}

// ---------------------------------------------------------------------------
// Kernel 1: bf16 MFMA projection, fp32->bf16 fused into staging (R12 form —
// measured equal to best). Tile 64m x 64n, BK=128, grid 256, XCD swizzle.
//   n < 1024:  Ea[m][n] = exp2(C*(acc+b1[n]));  else Eb[m][n-1024] = exp2(C*acc)
// ---------------------------------------------------------------------------
__global__ __launch_bounds__(256, 4) void proj_mfma_kernel(
    const float* __restrict__ lm, const float* __restrict__ W1,
    const float* __restrict__ b1, float* __restrict__ Ea, float* __restrict__ Eb)
{
    __shared__ ushort As[64][136];  // 136 us = 68 dw = 4 mod 32 banks: <=2-way, free
    __shared__ ushort Bs[64][136];

    const int tid  = threadIdx.x;
    const int lane = tid & 63;
    const int w    = tid >> 6;
    const int b    = blockIdx.x;          // 0..255
    const int xcd  = b & 7;
    const int idx  = b >> 3;              // 0..31
    const int nbase = (xcd * 4 + (idx & 3)) * 64;   // 0..2047
    const int mbase = (idx >> 2) * 64;              // 0..448
    const int wm   = w * 16;
    const int sel  = nbase >> 10;         // block-uniform: Wa(0)/Wb(1)
    const int nrow = nbase & 1023;

    const int frow = lane & 15;
    const int q8   = (lane >> 4) * 8;

    f32x4 acc[4] = {};

    for (int kb = 0; kb < HH; kb += 128) {
        __syncthreads();
        {
            int p = tid;
#pragma unroll
            for (int it = 0; it < 4; ++it, p += 256) {
                const int row = p >> 4, c8 = (p & 15) * 8;
                const float* pa = &lm[(mbase + row) * HH + kb + c8];
                *(uint4*)&As[row][c8] = pack8(*(const float4*)pa, *(const float4*)(pa + 4));
                const float* pw = &W1[(nrow + row) * 2048 + sel * 1024 + kb + c8];
                *(uint4*)&Bs[row][c8] = pack8(*(const float4*)pw, *(const float4*)(pw + 4));
            }
        }
        __syncthreads();

#pragma unroll
        for (int s = 0; s < 4; ++s) {
            const bf16x8 a = *(const bf16x8*)&As[wm + frow][s * 32 + q8];
#pragma unroll
            for (int nf = 0; nf < 4; ++nf) {
                const bf16x8 bb = *(const bf16x8*)&Bs[nf * 16 + frow][s * 32 + q8];
                acc[nf] = __builtin_amdgcn_mfma_f32_16x16x32_bf16(a, bb, acc[nf], 0, 0, 0);
            }
        }
    }

    // D mapping: col=lane&15 (n), row=(lane>>4)*4+reg (m)
    const int col = lane & 15;
    const int rq  = (lane >> 4) * 4;
    const int m0  = mbase + wm + rq;
    const bool isA = sel == 0;            // block-uniform
#pragma unroll
    for (int nf = 0; nf < 4; ++nf) {
        const int nn = (nrow + nf * 16 + col);
        if (isA) {
            const float bb = b1[nn];
#pragma unroll
            for (int r = 0; r < 4; ++r)
                Ea[(m0 + r) * HH + nn] = __builtin_amdgcn_exp2f(C_EXP * (acc[nf][r] + bb));
        } else {
#pragma unroll
            for (int r = 0; r < 4; ++r)
                Eb[(m0 + r) * HH + nn] = __builtin_amdgcn_exp2f(C_EXP * acc[nf][r]);
        }
    }
}

// ---------------------------------------------------------------------------
// Kernel 2: triangular pairwise contraction. LDS = exactly 32 KB -> 5
// blocks/CU (was 35.8 KB -> 4). tx-indexed tiles (Ea[j], Eb[j]) use an XOR
// float4-column swizzle (stride-64, reads <=2-way); ty-indexed tiles (Ea[i],
// Eb[i]) are broadcast-read (conflict-immune) -> plain stride-64. W2 read
// from global with wave-uniform indices (scalar loads); accumulators
// jj-packed f32x2 with scalar-broadcast FMA (no {w0,w1} interleave movs).
// ---------------------------------------------------------------------------
__global__ __launch_bounds__(256, 5) void pair_kernel(
    const float* __restrict__ Ea, const float* __restrict__ Eb,
    const float* __restrict__ W2, float* __restrict__ pbuf, int slice)
{
    // [0]=Ea[j] (xor), [1]=Ea[i] (plain), [2]=Eb[i] (plain), [3]=Eb[j] (xor)
    __shared__ float tl[4][32][64];   // 32768 B exactly

    const int tid = threadIdx.x;
    const int tx  = tid & 15;
    const int ty  = tid >> 4;         // 0..15

    int tt = blockIdx.x, bi = 0, rem = NT;          // triangular decode
    while (tt >= rem) { tt -= rem; --rem; ++bi; }
    const int bj    = bi + tt;
    const int ibase = bi * 32;
    const int jbase = bj * 32;
    const int k0    = blockIdx.y * slice;

    f32x2 aC0[2] = {}, aC1[2] = {};   // [ii], packed over jj
    const f32x2 one2 = {1.f, 1.f};

    for (int kb = 0; kb < slice; kb += 64) {
        if (kb) __syncthreads();
        {   // stage 4 tiles x 32 rows x 64 floats = 2048 float4, 8/thread
            int p = tid;
#pragma unroll
            for (int it = 0; it < 8; ++it, p += 256) {
                const int tile = p >> 9;             // compile-time per it
                const int row  = (p >> 4) & 31;
                const int c4   = p & 15;
                float4 v;
                if      (tile == 0) v = *(const float4*)&Ea[(jbase + row) * HH + k0 + kb + c4 * 4];
                else if (tile == 1) v = *(const float4*)&Ea[(ibase + row) * HH + k0 + kb + c4 * 4];
                else if (tile == 2) v = *(const float4*)&Eb[(ibase + row) * HH + k0 + kb + c4 * 4];
                else                v = *(const float4*)&Eb[(jbase + row) * HH + k0 + kb + c4 * 4];
                const int c4s = (tile == 0 || tile == 3) ? (c4 ^ (row & 15)) : c4;
                *(float4*)&tl[tile][row][c4s * 4] = v;
            }
        }
        __syncthreads();

#pragma unroll 4
        for (int h4 = 0; h4 < 16; ++h4) {
            const int sx = (h4 ^ tx) * 4;            // xor-swizzled column
            const float4 Aj0 = *(const float4*)&tl[0][tx][sx];
            const float4 Aj1 = *(const float4*)&tl[0][tx + 16][sx];
            const float4 Bj0 = *(const float4*)&tl[3][tx][sx];
            const float4 Bj1 = *(const float4*)&tl[3][tx + 16][sx];
            const float4 Ai0 = *(const float4*)&tl[1][ty][h4 * 4];
            const float4 Ai1 = *(const float4*)&tl[1][ty + 16][h4 * 4];
            const float4 Bi0 = *(const float4*)&tl[2][ty][h4 * 4];
            const float4 Bi1 = *(const float4*)&tl[2][ty + 16][h4 * 4];
            const float4 w0q = *(const float4*)&W2[k0 + kb + h4 * 4];      // uniform -> scalar
            const float4 w1q = *(const float4*)&W2[HH + k0 + kb + h4 * 4];

#define DO_H(AJ0v, AJ1v, BI0v, BI1v, AI0v, AI1v, BJ0v, BJ1v, W0s, W1s)        \
            {                                                                  \
                const f32x2 Aj = {AJ0v, AJ1v};                                 \
                const f32x2 Bj = {BJ0v, BJ1v};                                 \
                const f32x2 d0 = __builtin_elementwise_fma((f32x2){BI0v, BI0v}, Aj, one2); \
                const f32x2 d1 = __builtin_elementwise_fma((f32x2){BI1v, BI1v}, Aj, one2); \
                const f32x2 e0 = __builtin_elementwise_fma((f32x2){AI0v, AI0v}, Bj, one2); \
                const f32x2 e1 = __builtin_elementwise_fma((f32x2){AI1v, AI1v}, Bj, one2); \
                const float dp0 = d0.x * d0.y, dp1 = d1.x * d1.y;              \
                const float ep0 = e0.x * e0.y, ep1 = e1.x * e1.y;              \
                const float DR = __builtin_amdgcn_rcpf(dp0 * dp1);             \
                const float ER = __builtin_amdgcn_rcpf(ep0 * ep1);             \
                const f32x2 dq = (f32x2){DR, DR} * (f32x2){dp1, dp0};          \
                const f32x2 eq = (f32x2){ER, ER} * (f32x2){ep1, ep0};          \
                const f32x2 u0 = (f32x2){dq.x, dq.x} * d0.yx + (f32x2){eq.x, eq.x} * e0.yx; \
                const f32x2 u1 = (f32x2){dq.y, dq.y} * d1.yx + (f32x2){eq.y, eq.y} * e1.yx; \
                aC0[0] = __builtin_elementwise_fma(u0, (f32x2){(W0s), (W0s)}, aC0[0]); \
                aC1[0] = __builtin_elementwise_fma(u0, (f32x2){(W1s), (W1s)}, aC1[0]); \
                aC0[1] = __builtin_elementwise_fma(u1, (f32x2){(W0s), (W0s)}, aC0[1]); \
                aC1[1] = __builtin_elementwise_fma(u1, (f32x2){(W1s), (W1s)}, aC1[1]); \
            }
            DO_H(Aj0.x, Aj1.x, Bi0.x, Bi1.x, Ai0.x, Ai1.x, Bj0.x, Bj1.x, w0q.x, w1q.x)
            DO_H(Aj0.y, Aj1.y, Bi0.y, Bi1.y, Ai0.y, Ai1.y, Bj0.y, Bj1.y, w0q.y, w1q.y)
            DO_H(Aj0.z, Aj1.z, Bi0.z, Bi1.z, Ai0.z, Ai1.z, Bj0.z, Bj1.z, w0q.z, w1q.z)
            DO_H(Aj0.w, Aj1.w, Bi0.w, Bi1.w, Ai0.w, Ai1.w, Bj0.w, Bj1.w, w0q.w, w1q.w)
#undef DO_H
        }
    }

    // u0/u1 are jj-packed: value(ii,jj,c) = (c ? aC1 : aC0)[ii][jj]
    float* pb = pbuf + ((size_t)blockIdx.y * NTRI + blockIdx.x) * 2048;
#pragma unroll
    for (int ii = 0; ii < 2; ++ii)
#pragma unroll
        for (int jj = 0; jj < 2; ++jj) {
            const int li = ty + ii * 16, lj = tx + jj * 16;
            const f32x2 v = { jj ? aC0[ii].y : aC0[ii].x,
                              jj ? aC1[ii].y : aC1[ii].x };
            *(f32x2*)&pb[(li * 32 + lj) * 2] = v;
        }
}

// ---------------------------------------------------------------------------
// Kernel 3: combine (R12 form): out = wsum[c]+b2[c] - sum_z pbuf;
// scatter to (i,j) and (j,i). 1088 blocks, 2-way ILP on z.
// ---------------------------------------------------------------------------
__global__ __launch_bounds__(256) void combine_kernel(
    const float* __restrict__ pbuf, const float* __restrict__ W2,
    const float* __restrict__ b2, float* __restrict__ out, int nz)
{
    __shared__ float s_ws[2];

    const int tid = threadIdx.x;
    if (tid < 128) {
        const int c = tid >> 6, l = tid & 63;
        float s = 0.f;
#pragma unroll
        for (int q = 0; q < 4; ++q) {
            const float4 v = *(const float4*)&W2[c * HH + (l + q * 64) * 4];
            s += v.x + v.y + v.z + v.w;
        }
#pragma unroll
        for (int off = 32; off; off >>= 1) s += __shfl_down(s, off, 64);
        if (l == 0) s_ws[c] = s + b2[c];
    }
    __syncthreads();

    const int idx   = blockIdx.x * 256 + tid;   // 0 .. 136*2048-1
    const int t     = idx >> 11;                // block-uniform
    const int local = idx & 2047;
    int tt = t, bi = 0, rem = NT;
    while (tt >= rem) { tt -= rem; --rem; ++bi; }
    const int bj = bi + tt;

    float s0 = 0.f, s1 = 0.f;
    for (int z = 0; z < nz; z += 2) {   // nz is even
        s0 += pbuf[((size_t)z * NTRI + t) * 2048 + local];
        s1 += pbuf[((size_t)(z + 1) * NTRI + t) * 2048 + local];
    }
    const float s = s0 + s1;

    const int li = local >> 6;
    const int lj = (local >> 1) & 31;
    const int c  = local & 1;
    const float v = s_ws[c] - s;

    const int i = bi * 32 + li;
    const int j = bj * 32 + lj;
    out[(i * LL + j) * 2 + c] = v;
    out[(j * LL + i) * 2 + c] = v;   // diagonal tiles: same-value rewrite, benign
}

extern "C" void kernel_launch(void* const* d_in, const int* in_sizes, int n_in,
                              void* d_out, int out_size, void* d_ws, size_t ws_size,
                              hipStream_t stream)
{
    const float* lm = (const float*)d_in[0];
    const float* W1 = (const float*)d_in[1];
    const float* b1 = (const float*)d_in[2];
    const float* W2 = (const float*)d_in[3];
    const float* b2 = (const float*)d_in[4];
    float* out = (float*)d_out;

    char* ws = (char*)d_ws;
    float* Ea   = (float*)ws;                            // 2 MB
    float* Eb   = (float*)(ws + (2u << 20));             // 2 MB
    float* pbuf = (float*)(ws + (4u << 20) + 64);        // nz * 1.11 MB

    const size_t ubase = (4u << 20) + 64;
    const size_t pb16  = (size_t)16 * NTRI * 2048 * 4;   // 17.8 MB
    const int nz = (ws_size >= ubase + pb16) ? 16 : 8;   // ws_size const/session
    const int slice = HH / nz;

    proj_mfma_kernel<<<256, 256, 0, stream>>>(lm, W1, b1, Ea, Eb);
    pair_kernel<<<dim3(NTRI, nz), 256, 0, stream>>>(Ea, Eb, W2, pbuf, slice);
    combine_kernel<<<(NTRI * 2048) / 256, 256, 0, stream>>>(pbuf, W2, b2, out, nz);
}